// Round 17
// baseline (286.356 us; speedup 1.0000x reference)
//
#include <hip/hip_runtime.h>
#include <hip/hip_bf16.h>
#include <hip/hip_fp16.h>

#define NTOK 2048
#define DM   1024
#define DF   4096
#define NE   8
#define NROWS (NTOK * 2)
#define NSPLIT 4
#define KSPL (DF / NSPLIT)
#define FFN1_NG (32 * 16 * 8)   // 4096 gemm blocks in ffn1 launch

typedef _Float16 f16x8 __attribute__((ext_vector_type(8)));
typedef _Float16 f16x4 __attribute__((ext_vector_type(4)));
typedef float    f32x4 __attribute__((ext_vector_type(4)));
typedef unsigned u32x2 __attribute__((ext_vector_type(2)));

__device__ __forceinline__ void gload_lds16(const void* g, void* l) {
    __builtin_amdgcn_global_load_lds(
        (const __attribute__((address_space(1))) void*)g,
        (__attribute__((address_space(3))) void*)l, 16, 0, 0);
}

__device__ __forceinline__ u32x2 pack4(float4 v) {
    _Float16 a = (_Float16)v.x, b = (_Float16)v.y,
             c = (_Float16)v.z, d = (_Float16)v.w;
    unsigned ua = __builtin_bit_cast(unsigned short, a);
    unsigned ub = __builtin_bit_cast(unsigned short, b);
    unsigned uc = __builtin_bit_cast(unsigned short, c);
    unsigned ud = __builtin_bit_cast(unsigned short, d);
    u32x2 r;
    r[0] = ua | (ub << 16);
    r[1] = uc | (ud << 16);
    return r;
}

// ---------------- init ----------------
__global__ void k_init(int* counts, float* probs_sum) {
    int i = threadIdx.x;
    if (i < NE) { counts[i] = 0; probs_sum[i] = 0.f; }
}

// ---------------- shared-tile transpose helper: [64k][64n] fp32 -> [64n][64k] fp16 ----------------
__device__ __forceinline__ void transpose_tile(
    float* tile /*64*65 floats in LDS*/,
    const float* __restrict__ src, _Float16* __restrict__ dst,
    int K, int N, int k0, int n0, int tid)
{
    int tk = tid >> 4, tn = (tid & 15) << 2;
#pragma unroll
    for (int r = 0; r < 4; r++) {
        float4 v = *(const float4*)(src + (size_t)(k0 + tk + (r << 4)) * N + n0 + tn);
        float* trow = &tile[(tk + (r << 4)) * 65 + tn];
        trow[0] = v.x; trow[1] = v.y; trow[2] = v.z; trow[3] = v.w;
    }
    __syncthreads();
    int on = tid >> 2, ok = (tid & 3) << 4;
    unsigned pk[8];
#pragma unroll
    for (int p2 = 0; p2 < 8; p2++) {
        _Float16 a = (_Float16)tile[(ok + 2 * p2) * 65 + on];
        _Float16 b = (_Float16)tile[(ok + 2 * p2 + 1) * 65 + on];
        pk[p2] = (unsigned)(*(unsigned short*)&a) | ((unsigned)(*(unsigned short*)&b) << 16);
    }
    _Float16* d = dst + (size_t)(n0 + on) * K + k0 + ok;
    *(uint4*)d       = make_uint4(pk[0], pk[1], pk[2], pk[3]);
    *(uint4*)(d + 8) = make_uint4(pk[4], pk[5], pk[6], pk[7]);
}

// ---------------- fused pre-pass: router (blocks 0..127) + w1/w3 transpose ----------------
__global__ __launch_bounds__(256) void k_pre(
    const float* __restrict__ x, const float* __restrict__ rw,
    const float* __restrict__ w1, const float* __restrict__ w3,
    _Float16* __restrict__ WA, _Float16* __restrict__ WB,
    int* counts, float* probs_sum,
    int* pair_exp, int* pair_pos, float* topp)
{
    __shared__ float smem[64 * 65];
    int bid = blockIdx.x;
    int tid = threadIdx.x;

    if (bid >= 128) {
        int t = bid - 128;
        int z = t >> 10, xy = t & 1023;
        int e = z & 7;
        const float* src = ((z < 8) ? w1 : w3) + (size_t)e * DM * DF;
        _Float16* dst = ((z < 8) ? WA : WB) + (size_t)e * DF * DM;
        transpose_tile(smem, src, dst, DM, DF, (xy >> 6) << 6, (xy & 63) << 6, tid);
        return;
    }

    float* lprobs = smem;
    int* lcount = (int*)(smem + 8);
    int* lbase  = (int*)(smem + 16);
    if (tid < NE) { lprobs[tid] = 0.f; lcount[tid] = 0; }
    __syncthreads();

    int l16 = tid & 15;
    int t = bid * 16 + (tid >> 4);

    const float* xt = x + (size_t)t * DM;
    float acc[NE];
#pragma unroll
    for (int e = 0; e < NE; e++) acc[e] = 0.f;

#pragma unroll
    for (int i0 = 0; i0 < DM; i0 += 64) {
        int i = i0 + l16 * 4;
        float4 xv = *(const float4*)(xt + i);
#pragma unroll
        for (int e = 0; e < NE; e++) {
            float4 wv = *(const float4*)(rw + e * DM + i);
            acc[e] = fmaf(xv.x, wv.x, acc[e]);
            acc[e] = fmaf(xv.y, wv.y, acc[e]);
            acc[e] = fmaf(xv.z, wv.z, acc[e]);
            acc[e] = fmaf(xv.w, wv.w, acc[e]);
        }
    }
#pragma unroll
    for (int m = 1; m < 16; m <<= 1)
#pragma unroll
        for (int e = 0; e < NE; e++)
            acc[e] += __shfl_xor(acc[e], m);

    int i0e = 0, i1e = 0, r0 = 0, r1 = 0;
    if (l16 == 0) {
        float mx = acc[0];
#pragma unroll
        for (int e = 1; e < NE; e++) mx = fmaxf(mx, acc[e]);
        float p[NE]; float s = 0.f;
#pragma unroll
        for (int e = 0; e < NE; e++) { p[e] = expf(acc[e] - mx); s += p[e]; }
        float inv = 1.f / s;
#pragma unroll
        for (int e = 0; e < NE; e++) atomicAdd(&lprobs[e], p[e] * inv);

        i0e = 0;
#pragma unroll
        for (int e = 1; e < NE; e++) if (acc[e] > acc[i0e]) i0e = e;
        i1e = (i0e == 0) ? 1 : 0;
#pragma unroll
        for (int e = 0; e < NE; e++) if (e != i0e && acc[e] > acc[i1e]) i1e = e;

        float e1 = expf(acc[i1e] - acc[i0e]);
        float den = 1.f / (1.f + e1);
        topp[t * 2 + 0] = den;
        topp[t * 2 + 1] = e1 * den;
        pair_exp[t * 2 + 0] = i0e;
        pair_exp[t * 2 + 1] = i1e;
        r0 = atomicAdd(&lcount[i0e], 1);
        r1 = atomicAdd(&lcount[i1e], 1);
    }
    __syncthreads();
    if (tid < NE) {
        lbase[tid] = atomicAdd(&counts[tid], lcount[tid]);
        atomicAdd(&probs_sum[tid], lprobs[tid]);
    }
    __syncthreads();
    if (l16 == 0) {
        pair_pos[t * 2 + 0] = lbase[i0e] + r0;
        pair_pos[t * 2 + 1] = lbase[i1e] + r1;
    }
}

// ---------------- offsets + aux loss ----------------
__global__ void k_offsets(const int* counts, const float* probs_sum,
                          int* eoff, float* out_aux)
{
    if (threadIdx.x == 0 && blockIdx.x == 0) {
        int off = 0;
        for (int e = 0; e < NE; e++) { eoff[e] = off; off += counts[e]; }
        eoff[NE] = off;
        float aux = 0.f;
        for (int e = 0; e < NE; e++) {
            float ep = probs_sum[e] / (float)NTOK;
            aux += ep * ep;
        }
        out_aux[0] = 0.01f * (float)NE * aux;
    }
}

// ---------------- gather tokens into grouped rows (fp32 -> fp16) ----------------
__global__ __launch_bounds__(256) void k_gather(
    const float* __restrict__ x, const int* __restrict__ pair_exp,
    const int* __restrict__ pair_pos, const int* __restrict__ eoff,
    _Float16* __restrict__ Xg)
{
    int b = blockIdx.x;
    int t = b >> 1, s = b & 1;
    int e = pair_exp[t * 2 + s];
    int row = eoff[e] + pair_pos[t * 2 + s];
    int c = threadIdx.x << 2;
    float4 v = *(const float4*)(x + (size_t)t * DM + c);
    u32x2 o = pack4(v);
    *(u32x2*)(Xg + (size_t)row * DM + c) = o;
}

// ---------------- standalone transpose (fallback for w2) ----------------
__global__ __launch_bounds__(256) void k_transpose(
    const float* __restrict__ W, _Float16* __restrict__ Wt, int K, int N)
{
    __shared__ float tile[64 * 65];
    int e = blockIdx.z;
    transpose_tile(tile, W + (size_t)e * K * N, Wt + (size_t)e * N * K,
                   K, N, blockIdx.y << 6, blockIdx.x << 6, threadIdx.x);
}

// ---------------- fused FFN1 (BK=32, counted-vmcnt, XCD-chunked) + w2 transpose blocks ----------------
__global__ __launch_bounds__(256, 2) void k_ffn1(
    const _Float16* __restrict__ A, const _Float16* __restrict__ B1t,
    const _Float16* __restrict__ B3t, _Float16* __restrict__ H,
    const int* __restrict__ counts, const int* __restrict__ eoff,
    const float* __restrict__ w2, _Float16* __restrict__ W2T)
{
    __shared__ __align__(16) unsigned char smem[49152];
    int bid = blockIdx.x;
    int tid = threadIdx.x;

    if (bid >= FFN1_NG) {   // w2 transpose tile (fused mode only)
        int t = bid - FFN1_NG;
        int e = t >> 10, xy = t & 1023;
        transpose_tile((float*)smem, w2 + (size_t)e * DF * DM,
                       W2T + (size_t)e * DM * DF,
                       DF, DM, (xy >> 4) << 6, (xy & 15) << 6, tid);
        return;
    }

    // T1: bijective XCD-chunk swizzle (4096 = 8 XCDs x 512). Default round-robin
    // puts the 32 n-blocks sharing an A-panel on 8 different L2s; chunking gives
    // each XCD one expert's contiguous (m,n) sweep so A-panels are fetched once.
    int gid = ((bid & 7) << 9) | (bid >> 3);

    int e = gid >> 9;
    int m0 = ((gid >> 5) & 15) << 7;
    int n0 = (gid & 31) << 7;
    int cnt = counts[e];
    if (m0 >= cnt) return;
    int rb = eoff[e];

    int lane = tid & 63, w = tid >> 6;
    int wr = (w >> 1) << 6, wc = (w & 1) << 6;
    int l15 = lane & 15, l4 = lane >> 4;

    const _Float16* Ab  = A   + (size_t)(rb + m0) * DM;
    const _Float16* B1b = B1t + ((size_t)e * DF + n0) * DM;
    const _Float16* B3b = B3t + ((size_t)e * DF + n0) * DM;

    // staging chunk map: 512 chunks/tensor/buffer, 2 per thread; slot-XOR with (row>>1)&3
    int c0 = tid, c1 = tid + 256;
    int r0c = c0 >> 2, s0c = (c0 & 3) ^ ((r0c >> 1) & 3);
    int r1c = c1 >> 2, s1c = (c1 & 3) ^ ((r1c >> 1) & 3);
    size_t g0 = (size_t)r0c * DM + (s0c << 3);
    size_t g1 = (size_t)r1c * DM + (s1c << 3);

    f32x4 accg[4][4], accu[4][4];
#pragma unroll
    for (int i = 0; i < 4; i++)
#pragma unroll
        for (int j = 0; j < 4; j++) {
            accg[i][j] = (f32x4){0.f, 0.f, 0.f, 0.f};
            accu[i][j] = (f32x4){0.f, 0.f, 0.f, 0.f};
        }

    auto STAGE = [&](unsigned char* buf, int k0) {
        gload_lds16(Ab  + g0 + k0, buf + (c0 << 4));
        gload_lds16(Ab  + g1 + k0, buf + (c1 << 4));
        gload_lds16(B1b + g0 + k0, buf + 8192 + (c0 << 4));
        gload_lds16(B1b + g1 + k0, buf + 8192 + (c1 << 4));
        gload_lds16(B3b + g0 + k0, buf + 16384 + (c0 << 4));
        gload_lds16(B3b + g1 + k0, buf + 16384 + (c1 << 4));
    };
    auto COMPUTE = [&](const unsigned char* buf) {
        f16x8 af[4], b1f[4], b3f[4];
#pragma unroll
        for (int i = 0; i < 4; i++) {
            int r = wr + (i << 4) + l15;
            int s = l4 ^ ((r >> 1) & 3);
            af[i] = *(const f16x8*)(buf + (r << 6) + (s << 4));
        }
#pragma unroll
        for (int j = 0; j < 4; j++) {
            int r = wc + (j << 4) + l15;
            int s = l4 ^ ((r >> 1) & 3);
            int o = (r << 6) + (s << 4);
            b1f[j] = *(const f16x8*)(buf + 8192 + o);
            b3f[j] = *(const f16x8*)(buf + 16384 + o);
        }
        __builtin_amdgcn_s_setprio(1);
#pragma unroll
        for (int i = 0; i < 4; i++)
#pragma unroll
            for (int j = 0; j < 4; j++) {
                accg[i][j] = __builtin_amdgcn_mfma_f32_16x16x32_f16(af[i], b1f[j], accg[i][j], 0, 0, 0);
                accu[i][j] = __builtin_amdgcn_mfma_f32_16x16x32_f16(af[i], b3f[j], accu[i][j], 0, 0, 0);
            }
        __builtin_amdgcn_s_setprio(0);
    };

    unsigned char* cur = smem;
    unsigned char* nxt = smem + 24576;

    STAGE(cur, 0);
    for (int k = 32; k < DM; k += 32) {
        STAGE(nxt, k);                                  // 6 loads in flight for nxt
        __builtin_amdgcn_sched_barrier(0);
        asm volatile("s_waitcnt vmcnt(6)" ::: "memory"); // cur's 6 loads complete
        __builtin_amdgcn_s_barrier();
        __builtin_amdgcn_sched_barrier(0);
        COMPUTE(cur);
        __builtin_amdgcn_sched_barrier(0);
        __builtin_amdgcn_s_barrier();                    // all waves done reading cur
        unsigned char* tp = cur; cur = nxt; nxt = tp;
    }
    asm volatile("s_waitcnt vmcnt(0)" ::: "memory");
    __builtin_amdgcn_s_barrier();
    __builtin_amdgcn_sched_barrier(0);
    COMPUTE(cur);

#pragma unroll
    for (int i = 0; i < 4; i++) {
#pragma unroll
        for (int rr = 0; rr < 4; rr++) {
            int m = m0 + wr + (i << 4) + (l4 << 2) + rr;
            if (m < cnt) {
                size_t go = (size_t)(rb + m) * DF + n0 + wc + l15;
#pragma unroll
                for (int j = 0; j < 4; j++) {
                    float g = accg[i][j][rr];
                    float u = accu[i][j][rr];
                    float h = g / (1.f + __expf(-g)) * u;
                    H[go + (size_t)(j << 4)] = (_Float16)h;
                }
            }
        }
    }
}

// ---------------- split-K grouped GEMM (BK=32, counted-vmcnt, XCD-chunked, fp16 Yp) ----------------
__global__ __launch_bounds__(256, 3) void k_gemm2(
    const _Float16* __restrict__ A, const _Float16* __restrict__ Bt,
    _Float16* __restrict__ Yp,
    const int* __restrict__ counts, const int* __restrict__ eoff)
{
    __shared__ __align__(16) unsigned char smem[32768];

    // T1: bijective XCD-chunk swizzle of the flattened block id (4096 = 8 x 512).
    int flat = blockIdx.x + (blockIdx.y << 3) + (blockIdx.z << 7);
    int swz = ((flat & 7) << 9) + (flat >> 3);
    int bx = swz & 7, by = (swz >> 3) & 15, bz = swz >> 7;

    int e = bz >> 2, sp = bz & 3;
    int cnt = counts[e];
    int m0 = by << 7;
    if (m0 >= cnt) return;
    int n0 = bx << 7;
    int rb = eoff[e];

    int tid = threadIdx.x;
    int lane = tid & 63, w = tid >> 6;
    int wr = (w >> 1) << 6, wc = (w & 1) << 6;
    int l15 = lane & 15, l4 = lane >> 4;

    const _Float16* Ab = A + (size_t)(rb + m0) * DF;
    const _Float16* Bb = Bt + ((size_t)e * DM + n0) * DF;

    int c0 = tid, c1 = tid + 256;
    int r0c = c0 >> 2, s0c = (c0 & 3) ^ ((r0c >> 1) & 3);
    int r1c = c1 >> 2, s1c = (c1 & 3) ^ ((r1c >> 1) & 3);
    size_t g0 = (size_t)r0c * DF + (s0c << 3);
    size_t g1 = (size_t)r1c * DF + (s1c << 3);

    f32x4 acc[4][4];
#pragma unroll
    for (int i = 0; i < 4; i++)
#pragma unroll
        for (int j = 0; j < 4; j++) acc[i][j] = (f32x4){0.f, 0.f, 0.f, 0.f};

    auto STAGE = [&](unsigned char* buf, int k0) {
        gload_lds16(Ab + g0 + k0, buf + (c0 << 4));
        gload_lds16(Ab + g1 + k0, buf + (c1 << 4));
        gload_lds16(Bb + g0 + k0, buf + 8192 + (c0 << 4));
        gload_lds16(Bb + g1 + k0, buf + 8192 + (c1 << 4));
    };
    auto COMPUTE = [&](const unsigned char* buf) {
        f16x8 af[4], bfr[4];
#pragma unroll
        for (int i = 0; i < 4; i++) {
            int r = wr + (i << 4) + l15;
            int s = l4 ^ ((r >> 1) & 3);
            af[i] = *(const f16x8*)(buf + (r << 6) + (s << 4));
        }
#pragma unroll
        for (int j = 0; j < 4; j++) {
            int r = wc + (j << 4) + l15;
            int s = l4 ^ ((r >> 1) & 3);
            bfr[j] = *(const f16x8*)(buf + 8192 + (r << 6) + (s << 4));
        }
        __builtin_amdgcn_s_setprio(1);
#pragma unroll
        for (int i = 0; i < 4; i++)
#pragma unroll
            for (int j = 0; j < 4; j++)
                acc[i][j] = __builtin_amdgcn_mfma_f32_16x16x32_f16(af[i], bfr[j], acc[i][j], 0, 0, 0);
        __builtin_amdgcn_s_setprio(0);
    };

    unsigned char* cur = smem;
    unsigned char* nxt = smem + 16384;
    int kbase = sp * KSPL;

    STAGE(cur, kbase);
    for (int k = 32; k < KSPL; k += 32) {
        STAGE(nxt, kbase + k);
        __builtin_amdgcn_sched_barrier(0);
        asm volatile("s_waitcnt vmcnt(4)" ::: "memory");
        __builtin_amdgcn_s_barrier();
        __builtin_amdgcn_sched_barrier(0);
        COMPUTE(cur);
        __builtin_amdgcn_sched_barrier(0);
        __builtin_amdgcn_s_barrier();
        unsigned char* tp = cur; cur = nxt; nxt = tp;
    }
    asm volatile("s_waitcnt vmcnt(0)" ::: "memory");
    __builtin_amdgcn_s_barrier();
    __builtin_amdgcn_sched_barrier(0);
    COMPUTE(cur);

    _Float16* Yo = Yp + (size_t)sp * NROWS * DM;
#pragma unroll
    for (int i = 0; i < 4; i++) {
#pragma unroll
        for (int rr = 0; rr < 4; rr++) {
            int m = m0 + wr + (i << 4) + (l4 << 2) + rr;
            if (m < cnt) {
                size_t go = (size_t)(rb + m) * DM + n0 + wc + l15;
#pragma unroll
                for (int j = 0; j < 4; j++)
                    Yo[go + (size_t)(j << 4)] = (_Float16)acc[i][j][rr];
            }
        }
    }
}

// ---------------- combine (fp16 Yp partials) ----------------
__global__ __launch_bounds__(256) void k_combine(
    const _Float16* __restrict__ Yp,
    const int* __restrict__ pair_exp, const int* __restrict__ pair_pos,
    const float* __restrict__ topp, const int* __restrict__ eoff,
    float* __restrict__ out)
{
    int t = blockIdx.x;
    int c4 = threadIdx.x * 4;
    int e0 = pair_exp[t * 2], e1 = pair_exp[t * 2 + 1];
    size_t r0 = (size_t)(eoff[e0] + pair_pos[t * 2]);
    size_t r1 = (size_t)(eoff[e1] + pair_pos[t * 2 + 1]);
    float p0 = topp[t * 2], p1 = topp[t * 2 + 1];

    float4 a = make_float4(0.f, 0.f, 0.f, 0.f);
    float4 b = make_float4(0.f, 0.f, 0.f, 0.f);
#pragma unroll
    for (int sp = 0; sp < NSPLIT; sp++) {
        const _Float16* base = Yp + (size_t)sp * NROWS * DM;
        f16x4 va = *(const f16x4*)&base[r0 * DM + c4];
        f16x4 vb = *(const f16x4*)&base[r1 * DM + c4];
        a.x += (float)va[0]; a.y += (float)va[1]; a.z += (float)va[2]; a.w += (float)va[3];
        b.x += (float)vb[0]; b.y += (float)vb[1]; b.z += (float)vb[2]; b.w += (float)vb[3];
    }
    float4 o;
    o.x = p0 * a.x + p1 * b.x;
    o.y = p0 * a.y + p1 * b.y;
    o.z = p0 * a.z + p1 * b.z;
    o.w = p0 * a.w + p1 * b.w;
    *(float4*)&out[(size_t)t * DM + c4] = o;
}

extern "C" void kernel_launch(void* const* d_in, const int* in_sizes, int n_in,
                              void* d_out, int out_size, void* d_ws, size_t ws_size,
                              hipStream_t stream)
{
    const float* x  = (const float*)d_in[0];
    const float* rw = (const float*)d_in[1];
    const float* w1 = (const float*)d_in[2];
    const float* w3 = (const float*)d_in[3];
    const float* w2 = (const float*)d_in[4];
    float* out = (float*)d_out;

    char* ws = (char*)d_ws;
    int*   counts    = (int*)ws;
    float* probs_sum = (float*)(ws + 64);
    int*   eoff      = (int*)(ws + 128);
    int*   pair_exp  = (int*)(ws + 256);
    int*   pair_pos  = (int*)(ws + 256 + NROWS * 4);
    float* topp      = (float*)(ws + 256 + 2 * NROWS * 4);

    _Float16* Xg  = (_Float16*)(ws + ((size_t)1 << 20));    // 8 MiB
    _Float16* H   = (_Float16*)(ws + ((size_t)9 << 20));    // 32 MiB
    _Float16* WA  = (_Float16*)(ws + ((size_t)41 << 20));   // 64 MiB: w1t (then w2t in fallback)
    _Float16* WB  = (_Float16*)(ws + ((size_t)105 << 20));  // 64 MiB: w3t, then Yp (fp16, 32 MiB)
    _Float16* Yp  = WB;
    _Float16* W2T = (_Float16*)(ws + ((size_t)169 << 20));  // 64 MiB (fused mode only)

    bool fused = ws_size >= ((size_t)234 << 20);

    k_init<<<1, 64, 0, stream>>>(counts, probs_sum);
    k_pre<<<128 + 16384, 256, 0, stream>>>(x, rw, w1, w3, WA, WB,
                                           counts, probs_sum, pair_exp, pair_pos, topp);
    k_offsets<<<1, 1, 0, stream>>>(counts, probs_sum, eoff, out + (size_t)NTOK * DM);
    k_gather<<<NROWS, 256, 0, stream>>>(x, pair_exp, pair_pos, eoff, Xg);

    if (fused) {
        k_ffn1<<<FFN1_NG + 8192, 256, 0, stream>>>(Xg, WA, WB, H, counts, eoff, w2, W2T);
        k_gemm2<<<dim3(DM / 128, 16, NE * NSPLIT), 256, 0, stream>>>(H, W2T, Yp, counts, eoff);
    } else {
        k_ffn1<<<FFN1_NG, 256, 0, stream>>>(Xg, WA, WB, H, counts, eoff, w2, nullptr);
        k_transpose<<<dim3(DM / 64, DF / 64, NE), 256, 0, stream>>>(w2, WA, DF, DM);
        k_gemm2<<<dim3(DM / 128, 16, NE * NSPLIT), 256, 0, stream>>>(H, WA, Yp, counts, eoff);
    }

    k_combine<<<NTOK, 256, 0, stream>>>(Yp, pair_exp, pair_pos, topp, eoff, out);
}

// Round 18
// 267.433 us; speedup vs baseline: 1.0708x; 1.0708x over previous
//
#include <hip/hip_runtime.h>
#include <hip/hip_bf16.h>
#include <hip/hip_fp16.h>

#define NTOK 2048
#define DM   1024
#define DF   4096
#define NE   8
#define NROWS (NTOK * 2)
#define NSPLIT 4
#define KSPL (DF / NSPLIT)
#define FFN1_NG (32 * 16 * 8)   // 4096 gemm blocks in ffn1 launch

typedef _Float16 f16x8 __attribute__((ext_vector_type(8)));
typedef _Float16 f16x4 __attribute__((ext_vector_type(4)));
typedef float    f32x4 __attribute__((ext_vector_type(4)));
typedef unsigned u32x2 __attribute__((ext_vector_type(2)));

__device__ __forceinline__ void gload_lds16(const void* g, void* l) {
    __builtin_amdgcn_global_load_lds(
        (const __attribute__((address_space(1))) void*)g,
        (__attribute__((address_space(3))) void*)l, 16, 0, 0);
}

__device__ __forceinline__ u32x2 pack4(float4 v) {
    _Float16 a = (_Float16)v.x, b = (_Float16)v.y,
             c = (_Float16)v.z, d = (_Float16)v.w;
    unsigned ua = __builtin_bit_cast(unsigned short, a);
    unsigned ub = __builtin_bit_cast(unsigned short, b);
    unsigned uc = __builtin_bit_cast(unsigned short, c);
    unsigned ud = __builtin_bit_cast(unsigned short, d);
    u32x2 r;
    r[0] = ua | (ub << 16);
    r[1] = uc | (ud << 16);
    return r;
}

// ---------------- init ----------------
__global__ void k_init(int* counts, float* probs_sum) {
    int i = threadIdx.x;
    if (i < NE) { counts[i] = 0; probs_sum[i] = 0.f; }
}

// ---------------- shared-tile transpose helper: [64k][64n] fp32 -> [64n][64k] fp16 ----------------
__device__ __forceinline__ void transpose_tile(
    float* tile /*64*65 floats in LDS*/,
    const float* __restrict__ src, _Float16* __restrict__ dst,
    int K, int N, int k0, int n0, int tid)
{
    int tk = tid >> 4, tn = (tid & 15) << 2;
#pragma unroll
    for (int r = 0; r < 4; r++) {
        float4 v = *(const float4*)(src + (size_t)(k0 + tk + (r << 4)) * N + n0 + tn);
        float* trow = &tile[(tk + (r << 4)) * 65 + tn];
        trow[0] = v.x; trow[1] = v.y; trow[2] = v.z; trow[3] = v.w;
    }
    __syncthreads();
    int on = tid >> 2, ok = (tid & 3) << 4;
    unsigned pk[8];
#pragma unroll
    for (int p2 = 0; p2 < 8; p2++) {
        _Float16 a = (_Float16)tile[(ok + 2 * p2) * 65 + on];
        _Float16 b = (_Float16)tile[(ok + 2 * p2 + 1) * 65 + on];
        pk[p2] = (unsigned)(*(unsigned short*)&a) | ((unsigned)(*(unsigned short*)&b) << 16);
    }
    _Float16* d = dst + (size_t)(n0 + on) * K + k0 + ok;
    *(uint4*)d       = make_uint4(pk[0], pk[1], pk[2], pk[3]);
    *(uint4*)(d + 8) = make_uint4(pk[4], pk[5], pk[6], pk[7]);
}

// ---------------- fused pre-pass: router (blocks 0..127) + w1/w3 transpose ----------------
__global__ __launch_bounds__(256) void k_pre(
    const float* __restrict__ x, const float* __restrict__ rw,
    const float* __restrict__ w1, const float* __restrict__ w3,
    _Float16* __restrict__ WA, _Float16* __restrict__ WB,
    int* counts, float* probs_sum,
    int* pair_exp, int* pair_pos, float* topp)
{
    __shared__ float smem[64 * 65];
    int bid = blockIdx.x;
    int tid = threadIdx.x;

    if (bid >= 128) {
        int t = bid - 128;
        int z = t >> 10, xy = t & 1023;
        int e = z & 7;
        const float* src = ((z < 8) ? w1 : w3) + (size_t)e * DM * DF;
        _Float16* dst = ((z < 8) ? WA : WB) + (size_t)e * DF * DM;
        transpose_tile(smem, src, dst, DM, DF, (xy >> 6) << 6, (xy & 63) << 6, tid);
        return;
    }

    float* lprobs = smem;
    int* lcount = (int*)(smem + 8);
    int* lbase  = (int*)(smem + 16);
    if (tid < NE) { lprobs[tid] = 0.f; lcount[tid] = 0; }
    __syncthreads();

    int l16 = tid & 15;
    int t = bid * 16 + (tid >> 4);

    const float* xt = x + (size_t)t * DM;
    float acc[NE];
#pragma unroll
    for (int e = 0; e < NE; e++) acc[e] = 0.f;

#pragma unroll
    for (int i0 = 0; i0 < DM; i0 += 64) {
        int i = i0 + l16 * 4;
        float4 xv = *(const float4*)(xt + i);
#pragma unroll
        for (int e = 0; e < NE; e++) {
            float4 wv = *(const float4*)(rw + e * DM + i);
            acc[e] = fmaf(xv.x, wv.x, acc[e]);
            acc[e] = fmaf(xv.y, wv.y, acc[e]);
            acc[e] = fmaf(xv.z, wv.z, acc[e]);
            acc[e] = fmaf(xv.w, wv.w, acc[e]);
        }
    }
#pragma unroll
    for (int m = 1; m < 16; m <<= 1)
#pragma unroll
        for (int e = 0; e < NE; e++)
            acc[e] += __shfl_xor(acc[e], m);

    int i0e = 0, i1e = 0, r0 = 0, r1 = 0;
    if (l16 == 0) {
        float mx = acc[0];
#pragma unroll
        for (int e = 1; e < NE; e++) mx = fmaxf(mx, acc[e]);
        float p[NE]; float s = 0.f;
#pragma unroll
        for (int e = 0; e < NE; e++) { p[e] = expf(acc[e] - mx); s += p[e]; }
        float inv = 1.f / s;
#pragma unroll
        for (int e = 0; e < NE; e++) atomicAdd(&lprobs[e], p[e] * inv);

        i0e = 0;
#pragma unroll
        for (int e = 1; e < NE; e++) if (acc[e] > acc[i0e]) i0e = e;
        i1e = (i0e == 0) ? 1 : 0;
#pragma unroll
        for (int e = 0; e < NE; e++) if (e != i0e && acc[e] > acc[i1e]) i1e = e;

        float e1 = expf(acc[i1e] - acc[i0e]);
        float den = 1.f / (1.f + e1);
        topp[t * 2 + 0] = den;
        topp[t * 2 + 1] = e1 * den;
        pair_exp[t * 2 + 0] = i0e;
        pair_exp[t * 2 + 1] = i1e;
        r0 = atomicAdd(&lcount[i0e], 1);
        r1 = atomicAdd(&lcount[i1e], 1);
    }
    __syncthreads();
    if (tid < NE) {
        lbase[tid] = atomicAdd(&counts[tid], lcount[tid]);
        atomicAdd(&probs_sum[tid], lprobs[tid]);
    }
    __syncthreads();
    if (l16 == 0) {
        pair_pos[t * 2 + 0] = lbase[i0e] + r0;
        pair_pos[t * 2 + 1] = lbase[i1e] + r1;
    }
}

// ---------------- offsets + aux loss ----------------
__global__ void k_offsets(const int* counts, const float* probs_sum,
                          int* eoff, float* out_aux)
{
    if (threadIdx.x == 0 && blockIdx.x == 0) {
        int off = 0;
        for (int e = 0; e < NE; e++) { eoff[e] = off; off += counts[e]; }
        eoff[NE] = off;
        float aux = 0.f;
        for (int e = 0; e < NE; e++) {
            float ep = probs_sum[e] / (float)NTOK;
            aux += ep * ep;
        }
        out_aux[0] = 0.01f * (float)NE * aux;
    }
}

// ---------------- gather tokens into grouped rows (fp32 -> fp16) ----------------
__global__ __launch_bounds__(256) void k_gather(
    const float* __restrict__ x, const int* __restrict__ pair_exp,
    const int* __restrict__ pair_pos, const int* __restrict__ eoff,
    _Float16* __restrict__ Xg)
{
    int b = blockIdx.x;
    int t = b >> 1, s = b & 1;
    int e = pair_exp[t * 2 + s];
    int row = eoff[e] + pair_pos[t * 2 + s];
    int c = threadIdx.x << 2;
    float4 v = *(const float4*)(x + (size_t)t * DM + c);
    u32x2 o = pack4(v);
    *(u32x2*)(Xg + (size_t)row * DM + c) = o;
}

// ---------------- standalone transpose (fallback for w2) ----------------
__global__ __launch_bounds__(256) void k_transpose(
    const float* __restrict__ W, _Float16* __restrict__ Wt, int K, int N)
{
    __shared__ float tile[64 * 65];
    int e = blockIdx.z;
    transpose_tile(tile, W + (size_t)e * K * N, Wt + (size_t)e * N * K,
                   K, N, blockIdx.y << 6, blockIdx.x << 6, threadIdx.x);
}

// ---------------- fused FFN1 (BK=32, counted-vmcnt pipeline) + w2 transpose blocks ----------------
// NOTE: no XCD swizzle here — default round-robin already co-locates B-panel
// reuse partners (32 apart in bid ≡ same XCD mod 8); R17's chunk swizzle broke
// that and raised FETCH 214->307 MB.
__global__ __launch_bounds__(256, 2) void k_ffn1(
    const _Float16* __restrict__ A, const _Float16* __restrict__ B1t,
    const _Float16* __restrict__ B3t, _Float16* __restrict__ H,
    const int* __restrict__ counts, const int* __restrict__ eoff,
    const float* __restrict__ w2, _Float16* __restrict__ W2T)
{
    __shared__ __align__(16) unsigned char smem[49152];
    int bid = blockIdx.x;
    int tid = threadIdx.x;

    if (bid >= FFN1_NG) {   // w2 transpose tile (fused mode only)
        int t = bid - FFN1_NG;
        int e = t >> 10, xy = t & 1023;
        transpose_tile((float*)smem, w2 + (size_t)e * DF * DM,
                       W2T + (size_t)e * DM * DF,
                       DF, DM, (xy >> 4) << 6, (xy & 15) << 6, tid);
        return;
    }

    int e = bid >> 9;
    int m0 = ((bid >> 5) & 15) << 7;
    int n0 = (bid & 31) << 7;
    int cnt = counts[e];
    if (m0 >= cnt) return;
    int rb = eoff[e];

    int lane = tid & 63, w = tid >> 6;
    int wr = (w >> 1) << 6, wc = (w & 1) << 6;
    int l15 = lane & 15, l4 = lane >> 4;

    const _Float16* Ab  = A   + (size_t)(rb + m0) * DM;
    const _Float16* B1b = B1t + ((size_t)e * DF + n0) * DM;
    const _Float16* B3b = B3t + ((size_t)e * DF + n0) * DM;

    // staging chunk map: 512 chunks/tensor/buffer, 2 per thread; slot-XOR with (row>>1)&3
    int c0 = tid, c1 = tid + 256;
    int r0c = c0 >> 2, s0c = (c0 & 3) ^ ((r0c >> 1) & 3);
    int r1c = c1 >> 2, s1c = (c1 & 3) ^ ((r1c >> 1) & 3);
    size_t g0 = (size_t)r0c * DM + (s0c << 3);
    size_t g1 = (size_t)r1c * DM + (s1c << 3);

    f32x4 accg[4][4], accu[4][4];
#pragma unroll
    for (int i = 0; i < 4; i++)
#pragma unroll
        for (int j = 0; j < 4; j++) {
            accg[i][j] = (f32x4){0.f, 0.f, 0.f, 0.f};
            accu[i][j] = (f32x4){0.f, 0.f, 0.f, 0.f};
        }

    auto STAGE = [&](unsigned char* buf, int k0) {
        gload_lds16(Ab  + g0 + k0, buf + (c0 << 4));
        gload_lds16(Ab  + g1 + k0, buf + (c1 << 4));
        gload_lds16(B1b + g0 + k0, buf + 8192 + (c0 << 4));
        gload_lds16(B1b + g1 + k0, buf + 8192 + (c1 << 4));
        gload_lds16(B3b + g0 + k0, buf + 16384 + (c0 << 4));
        gload_lds16(B3b + g1 + k0, buf + 16384 + (c1 << 4));
    };
    auto COMPUTE = [&](const unsigned char* buf) {
        f16x8 af[4], b1f[4], b3f[4];
#pragma unroll
        for (int i = 0; i < 4; i++) {
            int r = wr + (i << 4) + l15;
            int s = l4 ^ ((r >> 1) & 3);
            af[i] = *(const f16x8*)(buf + (r << 6) + (s << 4));
        }
#pragma unroll
        for (int j = 0; j < 4; j++) {
            int r = wc + (j << 4) + l15;
            int s = l4 ^ ((r >> 1) & 3);
            int o = (r << 6) + (s << 4);
            b1f[j] = *(const f16x8*)(buf + 8192 + o);
            b3f[j] = *(const f16x8*)(buf + 16384 + o);
        }
        __builtin_amdgcn_s_setprio(1);
#pragma unroll
        for (int i = 0; i < 4; i++)
#pragma unroll
            for (int j = 0; j < 4; j++) {
                accg[i][j] = __builtin_amdgcn_mfma_f32_16x16x32_f16(af[i], b1f[j], accg[i][j], 0, 0, 0);
                accu[i][j] = __builtin_amdgcn_mfma_f32_16x16x32_f16(af[i], b3f[j], accu[i][j], 0, 0, 0);
            }
        __builtin_amdgcn_s_setprio(0);
    };

    unsigned char* cur = smem;
    unsigned char* nxt = smem + 24576;

    STAGE(cur, 0);
    for (int k = 32; k < DM; k += 32) {
        STAGE(nxt, k);                                  // 6 loads in flight for nxt
        __builtin_amdgcn_sched_barrier(0);
        asm volatile("s_waitcnt vmcnt(6)" ::: "memory"); // cur's 6 loads complete
        __builtin_amdgcn_s_barrier();
        __builtin_amdgcn_sched_barrier(0);
        COMPUTE(cur);
        __builtin_amdgcn_sched_barrier(0);
        __builtin_amdgcn_s_barrier();                    // all waves done reading cur
        unsigned char* tp = cur; cur = nxt; nxt = tp;
    }
    asm volatile("s_waitcnt vmcnt(0)" ::: "memory");
    __builtin_amdgcn_s_barrier();
    __builtin_amdgcn_sched_barrier(0);
    COMPUTE(cur);

#pragma unroll
    for (int i = 0; i < 4; i++) {
#pragma unroll
        for (int rr = 0; rr < 4; rr++) {
            int m = m0 + wr + (i << 4) + (l4 << 2) + rr;
            if (m < cnt) {
                size_t go = (size_t)(rb + m) * DF + n0 + wc + l15;
#pragma unroll
                for (int j = 0; j < 4; j++) {
                    float g = accg[i][j][rr];
                    float u = accu[i][j][rr];
                    float h = g / (1.f + __expf(-g)) * u;
                    H[go + (size_t)(j << 4)] = (_Float16)h;
                }
            }
        }
    }
}

// ---------------- split-K grouped GEMM (BK=32, counted-vmcnt, XCD-chunked, fp16 Yp) ----------------
__global__ __launch_bounds__(256, 3) void k_gemm2(
    const _Float16* __restrict__ A, const _Float16* __restrict__ Bt,
    _Float16* __restrict__ Yp,
    const int* __restrict__ counts, const int* __restrict__ eoff)
{
    __shared__ __align__(16) unsigned char smem[32768];

    // T1: bijective XCD-chunk swizzle of the flattened block id (4096 = 8 x 512).
    int flat = blockIdx.x + (blockIdx.y << 3) + (blockIdx.z << 7);
    int swz = ((flat & 7) << 9) + (flat >> 3);
    int bx = swz & 7, by = (swz >> 3) & 15, bz = swz >> 7;

    int e = bz >> 2, sp = bz & 3;
    int cnt = counts[e];
    int m0 = by << 7;
    if (m0 >= cnt) return;
    int n0 = bx << 7;
    int rb = eoff[e];

    int tid = threadIdx.x;
    int lane = tid & 63, w = tid >> 6;
    int wr = (w >> 1) << 6, wc = (w & 1) << 6;
    int l15 = lane & 15, l4 = lane >> 4;

    const _Float16* Ab = A + (size_t)(rb + m0) * DF;
    const _Float16* Bb = Bt + ((size_t)e * DM + n0) * DF;

    int c0 = tid, c1 = tid + 256;
    int r0c = c0 >> 2, s0c = (c0 & 3) ^ ((r0c >> 1) & 3);
    int r1c = c1 >> 2, s1c = (c1 & 3) ^ ((r1c >> 1) & 3);
    size_t g0 = (size_t)r0c * DF + (s0c << 3);
    size_t g1 = (size_t)r1c * DF + (s1c << 3);

    f32x4 acc[4][4];
#pragma unroll
    for (int i = 0; i < 4; i++)
#pragma unroll
        for (int j = 0; j < 4; j++) acc[i][j] = (f32x4){0.f, 0.f, 0.f, 0.f};

    auto STAGE = [&](unsigned char* buf, int k0) {
        gload_lds16(Ab + g0 + k0, buf + (c0 << 4));
        gload_lds16(Ab + g1 + k0, buf + (c1 << 4));
        gload_lds16(Bb + g0 + k0, buf + 8192 + (c0 << 4));
        gload_lds16(Bb + g1 + k0, buf + 8192 + (c1 << 4));
    };
    auto COMPUTE = [&](const unsigned char* buf) {
        f16x8 af[4], bfr[4];
#pragma unroll
        for (int i = 0; i < 4; i++) {
            int r = wr + (i << 4) + l15;
            int s = l4 ^ ((r >> 1) & 3);
            af[i] = *(const f16x8*)(buf + (r << 6) + (s << 4));
        }
#pragma unroll
        for (int j = 0; j < 4; j++) {
            int r = wc + (j << 4) + l15;
            int s = l4 ^ ((r >> 1) & 3);
            bfr[j] = *(const f16x8*)(buf + 8192 + (r << 6) + (s << 4));
        }
        __builtin_amdgcn_s_setprio(1);
#pragma unroll
        for (int i = 0; i < 4; i++)
#pragma unroll
            for (int j = 0; j < 4; j++)
                acc[i][j] = __builtin_amdgcn_mfma_f32_16x16x32_f16(af[i], bfr[j], acc[i][j], 0, 0, 0);
        __builtin_amdgcn_s_setprio(0);
    };

    unsigned char* cur = smem;
    unsigned char* nxt = smem + 16384;
    int kbase = sp * KSPL;

    STAGE(cur, kbase);
    for (int k = 32; k < KSPL; k += 32) {
        STAGE(nxt, kbase + k);
        __builtin_amdgcn_sched_barrier(0);
        asm volatile("s_waitcnt vmcnt(4)" ::: "memory");
        __builtin_amdgcn_s_barrier();
        __builtin_amdgcn_sched_barrier(0);
        COMPUTE(cur);
        __builtin_amdgcn_sched_barrier(0);
        __builtin_amdgcn_s_barrier();
        unsigned char* tp = cur; cur = nxt; nxt = tp;
    }
    asm volatile("s_waitcnt vmcnt(0)" ::: "memory");
    __builtin_amdgcn_s_barrier();
    __builtin_amdgcn_sched_barrier(0);
    COMPUTE(cur);

    _Float16* Yo = Yp + (size_t)sp * NROWS * DM;
#pragma unroll
    for (int i = 0; i < 4; i++) {
#pragma unroll
        for (int rr = 0; rr < 4; rr++) {
            int m = m0 + wr + (i << 4) + (l4 << 2) + rr;
            if (m < cnt) {
                size_t go = (size_t)(rb + m) * DM + n0 + wc + l15;
#pragma unroll
                for (int j = 0; j < 4; j++)
                    Yo[go + (size_t)(j << 4)] = (_Float16)acc[i][j][rr];
            }
        }
    }
}

// ---------------- combine (fp16 Yp partials) ----------------
__global__ __launch_bounds__(256) void k_combine(
    const _Float16* __restrict__ Yp,
    const int* __restrict__ pair_exp, const int* __restrict__ pair_pos,
    const float* __restrict__ topp, const int* __restrict__ eoff,
    float* __restrict__ out)
{
    int t = blockIdx.x;
    int c4 = threadIdx.x * 4;
    int e0 = pair_exp[t * 2], e1 = pair_exp[t * 2 + 1];
    size_t r0 = (size_t)(eoff[e0] + pair_pos[t * 2]);
    size_t r1 = (size_t)(eoff[e1] + pair_pos[t * 2 + 1]);
    float p0 = topp[t * 2], p1 = topp[t * 2 + 1];

    float4 a = make_float4(0.f, 0.f, 0.f, 0.f);
    float4 b = make_float4(0.f, 0.f, 0.f, 0.f);
#pragma unroll
    for (int sp = 0; sp < NSPLIT; sp++) {
        const _Float16* base = Yp + (size_t)sp * NROWS * DM;
        f16x4 va = *(const f16x4*)&base[r0 * DM + c4];
        f16x4 vb = *(const f16x4*)&base[r1 * DM + c4];
        a.x += (float)va[0]; a.y += (float)va[1]; a.z += (float)va[2]; a.w += (float)va[3];
        b.x += (float)vb[0]; b.y += (float)vb[1]; b.z += (float)vb[2]; b.w += (float)vb[3];
    }
    float4 o;
    o.x = p0 * a.x + p1 * b.x;
    o.y = p0 * a.y + p1 * b.y;
    o.z = p0 * a.z + p1 * b.z;
    o.w = p0 * a.w + p1 * b.w;
    *(float4*)&out[(size_t)t * DM + c4] = o;
}

extern "C" void kernel_launch(void* const* d_in, const int* in_sizes, int n_in,
                              void* d_out, int out_size, void* d_ws, size_t ws_size,
                              hipStream_t stream)
{
    const float* x  = (const float*)d_in[0];
    const float* rw = (const float*)d_in[1];
    const float* w1 = (const float*)d_in[2];
    const float* w3 = (const float*)d_in[3];
    const float* w2 = (const float*)d_in[4];
    float* out = (float*)d_out;

    char* ws = (char*)d_ws;
    int*   counts    = (int*)ws;
    float* probs_sum = (float*)(ws + 64);
    int*   eoff      = (int*)(ws + 128);
    int*   pair_exp  = (int*)(ws + 256);
    int*   pair_pos  = (int*)(ws + 256 + NROWS * 4);
    float* topp      = (float*)(ws + 256 + 2 * NROWS * 4);

    _Float16* Xg  = (_Float16*)(ws + ((size_t)1 << 20));    // 8 MiB
    _Float16* H   = (_Float16*)(ws + ((size_t)9 << 20));    // 32 MiB
    _Float16* WA  = (_Float16*)(ws + ((size_t)41 << 20));   // 64 MiB: w1t (then w2t in fallback)
    _Float16* WB  = (_Float16*)(ws + ((size_t)105 << 20));  // 64 MiB: w3t, then Yp (fp16, 32 MiB)
    _Float16* Yp  = WB;
    _Float16* W2T = (_Float16*)(ws + ((size_t)169 << 20));  // 64 MiB (fused mode only)

    bool fused = ws_size >= ((size_t)234 << 20);

    k_init<<<1, 64, 0, stream>>>(counts, probs_sum);
    k_pre<<<128 + 16384, 256, 0, stream>>>(x, rw, w1, w3, WA, WB,
                                           counts, probs_sum, pair_exp, pair_pos, topp);
    k_offsets<<<1, 1, 0, stream>>>(counts, probs_sum, eoff, out + (size_t)NTOK * DM);
    k_gather<<<NROWS, 256, 0, stream>>>(x, pair_exp, pair_pos, eoff, Xg);

    if (fused) {
        k_ffn1<<<FFN1_NG + 8192, 256, 0, stream>>>(Xg, WA, WB, H, counts, eoff, w2, W2T);
        k_gemm2<<<dim3(DM / 128, 16, NE * NSPLIT), 256, 0, stream>>>(H, W2T, Yp, counts, eoff);
    } else {
        k_ffn1<<<FFN1_NG, 256, 0, stream>>>(Xg, WA, WB, H, counts, eoff, w2, nullptr);
        k_transpose<<<dim3(DM / 64, DF / 64, NE), 256, 0, stream>>>(w2, WA, DF, DM);
        k_gemm2<<<dim3(DM / 128, 16, NE * NSPLIT), 256, 0, stream>>>(H, WA, Yp, counts, eoff);
    }

    k_combine<<<NTOK, 256, 0, stream>>>(Yp, pair_exp, pair_pos, topp, eoff, out);
}

// Round 19
// 264.710 us; speedup vs baseline: 1.0818x; 1.0103x over previous
//
#include <hip/hip_runtime.h>
#include <hip/hip_bf16.h>
#include <hip/hip_fp16.h>

#define NTOK 2048
#define DM   1024
#define DF   4096
#define NE   8
#define NROWS (NTOK * 2)
#define NSPLIT 4
#define KSPL (DF / NSPLIT)
#define FFN1_NG (32 * 16 * 8)   // 4096 gemm blocks in ffn1 launch

typedef _Float16 f16x8 __attribute__((ext_vector_type(8)));
typedef _Float16 f16x4 __attribute__((ext_vector_type(4)));
typedef float    f32x4 __attribute__((ext_vector_type(4)));
typedef unsigned u32x2 __attribute__((ext_vector_type(2)));

__device__ __forceinline__ void gload_lds16(const void* g, void* l) {
    __builtin_amdgcn_global_load_lds(
        (const __attribute__((address_space(1))) void*)g,
        (__attribute__((address_space(3))) void*)l, 16, 0, 0);
}

__device__ __forceinline__ u32x2 pack4(float4 v) {
    _Float16 a = (_Float16)v.x, b = (_Float16)v.y,
             c = (_Float16)v.z, d = (_Float16)v.w;
    unsigned ua = __builtin_bit_cast(unsigned short, a);
    unsigned ub = __builtin_bit_cast(unsigned short, b);
    unsigned uc = __builtin_bit_cast(unsigned short, c);
    unsigned ud = __builtin_bit_cast(unsigned short, d);
    u32x2 r;
    r[0] = ua | (ub << 16);
    r[1] = uc | (ud << 16);
    return r;
}

// ---------------- init ----------------
__global__ void k_init(int* counts, float* probs_sum) {
    int i = threadIdx.x;
    if (i < NE) { counts[i] = 0; probs_sum[i] = 0.f; }
}

// ---------------- shared-tile transpose helper: [64k][64n] fp32 -> [64n][64k] fp16 ----------------
__device__ __forceinline__ void transpose_tile(
    float* tile /*64*65 floats in LDS*/,
    const float* __restrict__ src, _Float16* __restrict__ dst,
    int K, int N, int k0, int n0, int tid)
{
    int tk = tid >> 4, tn = (tid & 15) << 2;
#pragma unroll
    for (int r = 0; r < 4; r++) {
        float4 v = *(const float4*)(src + (size_t)(k0 + tk + (r << 4)) * N + n0 + tn);
        float* trow = &tile[(tk + (r << 4)) * 65 + tn];
        trow[0] = v.x; trow[1] = v.y; trow[2] = v.z; trow[3] = v.w;
    }
    __syncthreads();
    int on = tid >> 2, ok = (tid & 3) << 4;
    unsigned pk[8];
#pragma unroll
    for (int p2 = 0; p2 < 8; p2++) {
        _Float16 a = (_Float16)tile[(ok + 2 * p2) * 65 + on];
        _Float16 b = (_Float16)tile[(ok + 2 * p2 + 1) * 65 + on];
        pk[p2] = (unsigned)(*(unsigned short*)&a) | ((unsigned)(*(unsigned short*)&b) << 16);
    }
    _Float16* d = dst + (size_t)(n0 + on) * K + k0 + ok;
    *(uint4*)d       = make_uint4(pk[0], pk[1], pk[2], pk[3]);
    *(uint4*)(d + 8) = make_uint4(pk[4], pk[5], pk[6], pk[7]);
}

// ---------------- fused pre-pass: router (blocks 0..127) + w1/w3 transpose ----------------
__global__ __launch_bounds__(256) void k_pre(
    const float* __restrict__ x, const float* __restrict__ rw,
    const float* __restrict__ w1, const float* __restrict__ w3,
    _Float16* __restrict__ WA, _Float16* __restrict__ WB,
    int* counts, float* probs_sum,
    int* pair_exp, int* pair_pos, float* topp)
{
    __shared__ float smem[64 * 65];
    int bid = blockIdx.x;
    int tid = threadIdx.x;

    if (bid >= 128) {
        int t = bid - 128;
        int z = t >> 10, xy = t & 1023;
        int e = z & 7;
        const float* src = ((z < 8) ? w1 : w3) + (size_t)e * DM * DF;
        _Float16* dst = ((z < 8) ? WA : WB) + (size_t)e * DF * DM;
        transpose_tile(smem, src, dst, DM, DF, (xy >> 6) << 6, (xy & 63) << 6, tid);
        return;
    }

    float* lprobs = smem;
    int* lcount = (int*)(smem + 8);
    int* lbase  = (int*)(smem + 16);
    if (tid < NE) { lprobs[tid] = 0.f; lcount[tid] = 0; }
    __syncthreads();

    int l16 = tid & 15;
    int t = bid * 16 + (tid >> 4);

    const float* xt = x + (size_t)t * DM;
    float acc[NE];
#pragma unroll
    for (int e = 0; e < NE; e++) acc[e] = 0.f;

#pragma unroll
    for (int i0 = 0; i0 < DM; i0 += 64) {
        int i = i0 + l16 * 4;
        float4 xv = *(const float4*)(xt + i);
#pragma unroll
        for (int e = 0; e < NE; e++) {
            float4 wv = *(const float4*)(rw + e * DM + i);
            acc[e] = fmaf(xv.x, wv.x, acc[e]);
            acc[e] = fmaf(xv.y, wv.y, acc[e]);
            acc[e] = fmaf(xv.z, wv.z, acc[e]);
            acc[e] = fmaf(xv.w, wv.w, acc[e]);
        }
    }
#pragma unroll
    for (int m = 1; m < 16; m <<= 1)
#pragma unroll
        for (int e = 0; e < NE; e++)
            acc[e] += __shfl_xor(acc[e], m);

    int i0e = 0, i1e = 0, r0 = 0, r1 = 0;
    if (l16 == 0) {
        float mx = acc[0];
#pragma unroll
        for (int e = 1; e < NE; e++) mx = fmaxf(mx, acc[e]);
        float p[NE]; float s = 0.f;
#pragma unroll
        for (int e = 0; e < NE; e++) { p[e] = expf(acc[e] - mx); s += p[e]; }
        float inv = 1.f / s;
#pragma unroll
        for (int e = 0; e < NE; e++) atomicAdd(&lprobs[e], p[e] * inv);

        i0e = 0;
#pragma unroll
        for (int e = 1; e < NE; e++) if (acc[e] > acc[i0e]) i0e = e;
        i1e = (i0e == 0) ? 1 : 0;
#pragma unroll
        for (int e = 0; e < NE; e++) if (e != i0e && acc[e] > acc[i1e]) i1e = e;

        float e1 = expf(acc[i1e] - acc[i0e]);
        float den = 1.f / (1.f + e1);
        topp[t * 2 + 0] = den;
        topp[t * 2 + 1] = e1 * den;
        pair_exp[t * 2 + 0] = i0e;
        pair_exp[t * 2 + 1] = i1e;
        r0 = atomicAdd(&lcount[i0e], 1);
        r1 = atomicAdd(&lcount[i1e], 1);
    }
    __syncthreads();
    if (tid < NE) {
        lbase[tid] = atomicAdd(&counts[tid], lcount[tid]);
        atomicAdd(&probs_sum[tid], lprobs[tid]);
    }
    __syncthreads();
    if (l16 == 0) {
        pair_pos[t * 2 + 0] = lbase[i0e] + r0;
        pair_pos[t * 2 + 1] = lbase[i1e] + r1;
    }
}

// ---------------- offsets + aux loss ----------------
__global__ void k_offsets(const int* counts, const float* probs_sum,
                          int* eoff, float* out_aux)
{
    if (threadIdx.x == 0 && blockIdx.x == 0) {
        int off = 0;
        for (int e = 0; e < NE; e++) { eoff[e] = off; off += counts[e]; }
        eoff[NE] = off;
        float aux = 0.f;
        for (int e = 0; e < NE; e++) {
            float ep = probs_sum[e] / (float)NTOK;
            aux += ep * ep;
        }
        out_aux[0] = 0.01f * (float)NE * aux;
    }
}

// ---------------- gather tokens into grouped rows (fp32 -> fp16) ----------------
__global__ __launch_bounds__(256) void k_gather(
    const float* __restrict__ x, const int* __restrict__ pair_exp,
    const int* __restrict__ pair_pos, const int* __restrict__ eoff,
    _Float16* __restrict__ Xg)
{
    int b = blockIdx.x;
    int t = b >> 1, s = b & 1;
    int e = pair_exp[t * 2 + s];
    int row = eoff[e] + pair_pos[t * 2 + s];
    int c = threadIdx.x << 2;
    float4 v = *(const float4*)(x + (size_t)t * DM + c);
    u32x2 o = pack4(v);
    *(u32x2*)(Xg + (size_t)row * DM + c) = o;
}

// ---------------- standalone transpose (fallback for w2) ----------------
__global__ __launch_bounds__(256) void k_transpose(
    const float* __restrict__ W, _Float16* __restrict__ Wt, int K, int N)
{
    __shared__ float tile[64 * 65];
    int e = blockIdx.z;
    transpose_tile(tile, W + (size_t)e * K * N, Wt + (size_t)e * N * K,
                   K, N, blockIdx.y << 6, blockIdx.x << 6, threadIdx.x);
}

// ---------------- fused FFN1 (BK=32, depth-2 counted-vmcnt pipeline) + w2 transpose blocks ----------------
// Depth-2 prefetch: 3 LDS buffers, tiles t/t+1/t+2 in flight, each tile's loads
// covered by TWO compute phases (~550cy vs ~900cy HBM latency).
__global__ __launch_bounds__(256, 2) void k_ffn1(
    const _Float16* __restrict__ A, const _Float16* __restrict__ B1t,
    const _Float16* __restrict__ B3t, _Float16* __restrict__ H,
    const int* __restrict__ counts, const int* __restrict__ eoff,
    const float* __restrict__ w2, _Float16* __restrict__ W2T)
{
    __shared__ __align__(16) unsigned char smem[73728];   // 3 x 24 KB
    int bid = blockIdx.x;
    int tid = threadIdx.x;

    if (bid >= FFN1_NG) {   // w2 transpose tile (fused mode only)
        int t = bid - FFN1_NG;
        int e = t >> 10, xy = t & 1023;
        transpose_tile((float*)smem, w2 + (size_t)e * DF * DM,
                       W2T + (size_t)e * DM * DF,
                       DF, DM, (xy >> 4) << 6, (xy & 15) << 6, tid);
        return;
    }

    int e = bid >> 9;
    int m0 = ((bid >> 5) & 15) << 7;
    int n0 = (bid & 31) << 7;
    int cnt = counts[e];
    if (m0 >= cnt) return;
    int rb = eoff[e];

    int lane = tid & 63, w = tid >> 6;
    int wr = (w >> 1) << 6, wc = (w & 1) << 6;
    int l15 = lane & 15, l4 = lane >> 4;

    const _Float16* Ab  = A   + (size_t)(rb + m0) * DM;
    const _Float16* B1b = B1t + ((size_t)e * DF + n0) * DM;
    const _Float16* B3b = B3t + ((size_t)e * DF + n0) * DM;

    // staging chunk map: 512 chunks/tensor/buffer, 2 per thread; slot-XOR with (row>>1)&3
    int c0 = tid, c1 = tid + 256;
    int r0c = c0 >> 2, s0c = (c0 & 3) ^ ((r0c >> 1) & 3);
    int r1c = c1 >> 2, s1c = (c1 & 3) ^ ((r1c >> 1) & 3);
    size_t g0 = (size_t)r0c * DM + (s0c << 3);
    size_t g1 = (size_t)r1c * DM + (s1c << 3);

    f32x4 accg[4][4], accu[4][4];
#pragma unroll
    for (int i = 0; i < 4; i++)
#pragma unroll
        for (int j = 0; j < 4; j++) {
            accg[i][j] = (f32x4){0.f, 0.f, 0.f, 0.f};
            accu[i][j] = (f32x4){0.f, 0.f, 0.f, 0.f};
        }

    auto STAGE = [&](unsigned char* buf, int k0) {
        gload_lds16(Ab  + g0 + k0, buf + (c0 << 4));
        gload_lds16(Ab  + g1 + k0, buf + (c1 << 4));
        gload_lds16(B1b + g0 + k0, buf + 8192 + (c0 << 4));
        gload_lds16(B1b + g1 + k0, buf + 8192 + (c1 << 4));
        gload_lds16(B3b + g0 + k0, buf + 16384 + (c0 << 4));
        gload_lds16(B3b + g1 + k0, buf + 16384 + (c1 << 4));
    };
    auto COMPUTE = [&](const unsigned char* buf) {
        f16x8 af[4], b1f[4], b3f[4];
#pragma unroll
        for (int i = 0; i < 4; i++) {
            int r = wr + (i << 4) + l15;
            int s = l4 ^ ((r >> 1) & 3);
            af[i] = *(const f16x8*)(buf + (r << 6) + (s << 4));
        }
#pragma unroll
        for (int j = 0; j < 4; j++) {
            int r = wc + (j << 4) + l15;
            int s = l4 ^ ((r >> 1) & 3);
            int o = (r << 6) + (s << 4);
            b1f[j] = *(const f16x8*)(buf + 8192 + o);
            b3f[j] = *(const f16x8*)(buf + 16384 + o);
        }
        __builtin_amdgcn_s_setprio(1);
#pragma unroll
        for (int i = 0; i < 4; i++)
#pragma unroll
            for (int j = 0; j < 4; j++) {
                accg[i][j] = __builtin_amdgcn_mfma_f32_16x16x32_f16(af[i], b1f[j], accg[i][j], 0, 0, 0);
                accu[i][j] = __builtin_amdgcn_mfma_f32_16x16x32_f16(af[i], b3f[j], accu[i][j], 0, 0, 0);
            }
        __builtin_amdgcn_s_setprio(0);
    };

    unsigned char* b0 = smem;
    unsigned char* b1 = smem + 24576;
    unsigned char* b2 = smem + 49152;

    STAGE(b0, 0);
    STAGE(b1, 32);
    for (int k = 64; k < DM; k += 32) {
        STAGE(b2, k);                                     // tiles t,t+1,t+2 in flight (18 loads)
        __builtin_amdgcn_sched_barrier(0);
        asm volatile("s_waitcnt vmcnt(12)" ::: "memory"); // oldest tile's 6 loads complete
        __builtin_amdgcn_s_barrier();
        __builtin_amdgcn_sched_barrier(0);
        COMPUTE(b0);
        __builtin_amdgcn_sched_barrier(0);
        __builtin_amdgcn_s_barrier();                     // all waves done reading b0
        unsigned char* tp = b0; b0 = b1; b1 = b2; b2 = tp;
    }
    // tail: tiles b0, b1 still staged
    __builtin_amdgcn_sched_barrier(0);
    asm volatile("s_waitcnt vmcnt(6)" ::: "memory");
    __builtin_amdgcn_s_barrier();
    __builtin_amdgcn_sched_barrier(0);
    COMPUTE(b0);
    __builtin_amdgcn_sched_barrier(0);
    asm volatile("s_waitcnt vmcnt(0)" ::: "memory");
    __builtin_amdgcn_s_barrier();
    __builtin_amdgcn_sched_barrier(0);
    COMPUTE(b1);

#pragma unroll
    for (int i = 0; i < 4; i++) {
#pragma unroll
        for (int rr = 0; rr < 4; rr++) {
            int m = m0 + wr + (i << 4) + (l4 << 2) + rr;
            if (m < cnt) {
                size_t go = (size_t)(rb + m) * DF + n0 + wc + l15;
#pragma unroll
                for (int j = 0; j < 4; j++) {
                    float g = accg[i][j][rr];
                    float u = accu[i][j][rr];
                    float h = g / (1.f + __expf(-g)) * u;
                    H[go + (size_t)(j << 4)] = (_Float16)h;
                }
            }
        }
    }
}

// ---------------- split-K grouped GEMM (BK=32, depth-2 vmcnt, XCD-chunked, fp16 Yp) ----------------
__global__ __launch_bounds__(256, 3) void k_gemm2(
    const _Float16* __restrict__ A, const _Float16* __restrict__ Bt,
    _Float16* __restrict__ Yp,
    const int* __restrict__ counts, const int* __restrict__ eoff)
{
    __shared__ __align__(16) unsigned char smem[49152];   // 3 x 16 KB

    // T1: bijective XCD-chunk swizzle of the flattened block id (4096 = 8 x 512).
    int flat = blockIdx.x + (blockIdx.y << 3) + (blockIdx.z << 7);
    int swz = ((flat & 7) << 9) + (flat >> 3);
    int bx = swz & 7, by = (swz >> 3) & 15, bz = swz >> 7;

    int e = bz >> 2, sp = bz & 3;
    int cnt = counts[e];
    int m0 = by << 7;
    if (m0 >= cnt) return;
    int n0 = bx << 7;
    int rb = eoff[e];

    int tid = threadIdx.x;
    int lane = tid & 63, w = tid >> 6;
    int wr = (w >> 1) << 6, wc = (w & 1) << 6;
    int l15 = lane & 15, l4 = lane >> 4;

    const _Float16* Ab = A + (size_t)(rb + m0) * DF;
    const _Float16* Bb = Bt + ((size_t)e * DM + n0) * DF;

    int c0 = tid, c1 = tid + 256;
    int r0c = c0 >> 2, s0c = (c0 & 3) ^ ((r0c >> 1) & 3);
    int r1c = c1 >> 2, s1c = (c1 & 3) ^ ((r1c >> 1) & 3);
    size_t g0 = (size_t)r0c * DF + (s0c << 3);
    size_t g1 = (size_t)r1c * DF + (s1c << 3);

    f32x4 acc[4][4];
#pragma unroll
    for (int i = 0; i < 4; i++)
#pragma unroll
        for (int j = 0; j < 4; j++) acc[i][j] = (f32x4){0.f, 0.f, 0.f, 0.f};

    auto STAGE = [&](unsigned char* buf, int k0) {
        gload_lds16(Ab + g0 + k0, buf + (c0 << 4));
        gload_lds16(Ab + g1 + k0, buf + (c1 << 4));
        gload_lds16(Bb + g0 + k0, buf + 8192 + (c0 << 4));
        gload_lds16(Bb + g1 + k0, buf + 8192 + (c1 << 4));
    };
    auto COMPUTE = [&](const unsigned char* buf) {
        f16x8 af[4], bfr[4];
#pragma unroll
        for (int i = 0; i < 4; i++) {
            int r = wr + (i << 4) + l15;
            int s = l4 ^ ((r >> 1) & 3);
            af[i] = *(const f16x8*)(buf + (r << 6) + (s << 4));
        }
#pragma unroll
        for (int j = 0; j < 4; j++) {
            int r = wc + (j << 4) + l15;
            int s = l4 ^ ((r >> 1) & 3);
            bfr[j] = *(const f16x8*)(buf + 8192 + (r << 6) + (s << 4));
        }
        __builtin_amdgcn_s_setprio(1);
#pragma unroll
        for (int i = 0; i < 4; i++)
#pragma unroll
            for (int j = 0; j < 4; j++)
                acc[i][j] = __builtin_amdgcn_mfma_f32_16x16x32_f16(af[i], bfr[j], acc[i][j], 0, 0, 0);
        __builtin_amdgcn_s_setprio(0);
    };

    unsigned char* b0 = smem;
    unsigned char* b1 = smem + 16384;
    unsigned char* b2 = smem + 32768;
    int kbase = sp * KSPL;

    STAGE(b0, kbase);
    STAGE(b1, kbase + 32);
    for (int k = 64; k < KSPL; k += 32) {
        STAGE(b2, kbase + k);                            // 12 loads in flight
        __builtin_amdgcn_sched_barrier(0);
        asm volatile("s_waitcnt vmcnt(8)" ::: "memory"); // oldest tile's 4 loads complete
        __builtin_amdgcn_s_barrier();
        __builtin_amdgcn_sched_barrier(0);
        COMPUTE(b0);
        __builtin_amdgcn_sched_barrier(0);
        __builtin_amdgcn_s_barrier();
        unsigned char* tp = b0; b0 = b1; b1 = b2; b2 = tp;
    }
    __builtin_amdgcn_sched_barrier(0);
    asm volatile("s_waitcnt vmcnt(4)" ::: "memory");
    __builtin_amdgcn_s_barrier();
    __builtin_amdgcn_sched_barrier(0);
    COMPUTE(b0);
    __builtin_amdgcn_sched_barrier(0);
    asm volatile("s_waitcnt vmcnt(0)" ::: "memory");
    __builtin_amdgcn_s_barrier();
    __builtin_amdgcn_sched_barrier(0);
    COMPUTE(b1);

    _Float16* Yo = Yp + (size_t)sp * NROWS * DM;
#pragma unroll
    for (int i = 0; i < 4; i++) {
#pragma unroll
        for (int rr = 0; rr < 4; rr++) {
            int m = m0 + wr + (i << 4) + (l4 << 2) + rr;
            if (m < cnt) {
                size_t go = (size_t)(rb + m) * DM + n0 + wc + l15;
#pragma unroll
                for (int j = 0; j < 4; j++)
                    Yo[go + (size_t)(j << 4)] = (_Float16)acc[i][j][rr];
            }
        }
    }
}

// ---------------- combine (fp16 Yp partials) ----------------
__global__ __launch_bounds__(256) void k_combine(
    const _Float16* __restrict__ Yp,
    const int* __restrict__ pair_exp, const int* __restrict__ pair_pos,
    const float* __restrict__ topp, const int* __restrict__ eoff,
    float* __restrict__ out)
{
    int t = blockIdx.x;
    int c4 = threadIdx.x * 4;
    int e0 = pair_exp[t * 2], e1 = pair_exp[t * 2 + 1];
    size_t r0 = (size_t)(eoff[e0] + pair_pos[t * 2]);
    size_t r1 = (size_t)(eoff[e1] + pair_pos[t * 2 + 1]);
    float p0 = topp[t * 2], p1 = topp[t * 2 + 1];

    float4 a = make_float4(0.f, 0.f, 0.f, 0.f);
    float4 b = make_float4(0.f, 0.f, 0.f, 0.f);
#pragma unroll
    for (int sp = 0; sp < NSPLIT; sp++) {
        const _Float16* base = Yp + (size_t)sp * NROWS * DM;
        f16x4 va = *(const f16x4*)&base[r0 * DM + c4];
        f16x4 vb = *(const f16x4*)&base[r1 * DM + c4];
        a.x += (float)va[0]; a.y += (float)va[1]; a.z += (float)va[2]; a.w += (float)va[3];
        b.x += (float)vb[0]; b.y += (float)vb[1]; b.z += (float)vb[2]; b.w += (float)vb[3];
    }
    float4 o;
    o.x = p0 * a.x + p1 * b.x;
    o.y = p0 * a.y + p1 * b.y;
    o.z = p0 * a.z + p1 * b.z;
    o.w = p0 * a.w + p1 * b.w;
    *(float4*)&out[(size_t)t * DM + c4] = o;
}

extern "C" void kernel_launch(void* const* d_in, const int* in_sizes, int n_in,
                              void* d_out, int out_size, void* d_ws, size_t ws_size,
                              hipStream_t stream)
{
    const float* x  = (const float*)d_in[0];
    const float* rw = (const float*)d_in[1];
    const float* w1 = (const float*)d_in[2];
    const float* w3 = (const float*)d_in[3];
    const float* w2 = (const float*)d_in[4];
    float* out = (float*)d_out;

    char* ws = (char*)d_ws;
    int*   counts    = (int*)ws;
    float* probs_sum = (float*)(ws + 64);
    int*   eoff      = (int*)(ws + 128);
    int*   pair_exp  = (int*)(ws + 256);
    int*   pair_pos  = (int*)(ws + 256 + NROWS * 4);
    float* topp      = (float*)(ws + 256 + 2 * NROWS * 4);

    _Float16* Xg  = (_Float16*)(ws + ((size_t)1 << 20));    // 8 MiB
    _Float16* H   = (_Float16*)(ws + ((size_t)9 << 20));    // 32 MiB
    _Float16* WA  = (_Float16*)(ws + ((size_t)41 << 20));   // 64 MiB: w1t (then w2t in fallback)
    _Float16* WB  = (_Float16*)(ws + ((size_t)105 << 20));  // 64 MiB: w3t, then Yp (fp16, 32 MiB)
    _Float16* Yp  = WB;
    _Float16* W2T = (_Float16*)(ws + ((size_t)169 << 20));  // 64 MiB (fused mode only)

    bool fused = ws_size >= ((size_t)234 << 20);

    k_init<<<1, 64, 0, stream>>>(counts, probs_sum);
    k_pre<<<128 + 16384, 256, 0, stream>>>(x, rw, w1, w3, WA, WB,
                                           counts, probs_sum, pair_exp, pair_pos, topp);
    k_offsets<<<1, 1, 0, stream>>>(counts, probs_sum, eoff, out + (size_t)NTOK * DM);
    k_gather<<<NROWS, 256, 0, stream>>>(x, pair_exp, pair_pos, eoff, Xg);

    if (fused) {
        k_ffn1<<<FFN1_NG + 8192, 256, 0, stream>>>(Xg, WA, WB, H, counts, eoff, w2, W2T);
        k_gemm2<<<dim3(DM / 128, 16, NE * NSPLIT), 256, 0, stream>>>(H, W2T, Yp, counts, eoff);
    } else {
        k_ffn1<<<FFN1_NG, 256, 0, stream>>>(Xg, WA, WB, H, counts, eoff, w2, nullptr);
        k_transpose<<<dim3(DM / 64, DF / 64, NE), 256, 0, stream>>>(w2, WA, DF, DM);
        k_gemm2<<<dim3(DM / 128, 16, NE * NSPLIT), 256, 0, stream>>>(H, WA, Yp, counts, eoff);
    }

    k_combine<<<NTOK, 256, 0, stream>>>(Yp, pair_exp, pair_pos, topp, eoff, out);
}